// Round 2
// baseline (11481.405 us; speedup 1.0000x reference)
//
#include <hip/hip_runtime.h>
#include <hip/hip_bf16.h>

typedef __bf16 bf16_t;
typedef __bf16 bf16x8 __attribute__((ext_vector_type(8)));
typedef float floatx4 __attribute__((ext_vector_type(4)));

#define LAYERS 8
#define BATCH  64
#define TSEQ   256
#define HDIM   512
#define GDIM   2048   // 4*H
#define UNITS  16     // LSTM units per CU slice
#define NROWS  64     // gate rows per CU slice (16 each of i,f,g,o)
// WROW=1048: row stride 2096 B = 524 dwords == 12 mod 32 banks -> consecutive
// l15 lanes land 12 banks apart => ~2-way aliasing (free, m136). Old 1032
// (stride==4 mod 32) gave 8-way (2.9x cost, 1.5e8 SQ_LDS_BANK_CONFLICT in R1).
#define WROW   1048

// LDS layout (bytes)
#define W_OFF      0
#define W_BYTES    (NROWS * WROW * 2)          // 134144
#define GATES_OFF  (W_OFF + W_BYTES)           // fp32 [64 batch][64 gates]
#define GATES_BYTES (BATCH * NROWS * 4)        // 16384
#define C_OFF      (GATES_OFF + GATES_BYTES)   // fp32 [64 batch][16 units]
#define C_BYTES    (BATCH * UNITS * 4)         // 4096
#define BIAS_OFF   (C_OFF + C_BYTES)           // fp32 [64]
#define BIAS_BYTES (NROWS * 4)                 // 256
#define LDS_TOTAL  (BIAS_OFF + BIAS_BYTES)     // 154880  (< 160 KiB)

__device__ __forceinline__ floatx4 mfma16(bf16x8 a, bf16x8 b, floatx4 c) {
    return __builtin_amdgcn_mfma_f32_16x16x32_bf16(a, b, c, 0, 0, 0);
}

__device__ __forceinline__ float sigm(float x) {
    return 1.0f / (1.0f + __expf(-x));
}

// Flag-array grid barrier. Each block publishes its OWN generation flag
// (plain agent-scope store -- no contended RMW like cg::grid.sync(), whose
// 256 serialized cross-XCD atomic RMWs cost ~35 us/superstep in R1).
// 256 spinner threads each watch one block's flag; all poll loads are in
// flight simultaneously (one L3 latency per round).
// Signed-distance compare makes it safe against (a) the 0xAA ws poison
// (0xAAAAAAAA - small gen is negative -> keeps spinning) and (b) a fast
// block overwriting its flag with gen+1 before a laggard polls (+1 -> pass).
__device__ __forceinline__ void grid_barrier(unsigned* flags, unsigned gen,
                                             int blk, int tid) {
    __syncthreads();
    // release: drain this thread's stores, write back dirty L2 (cross-XCD vis)
    __builtin_amdgcn_fence(__ATOMIC_RELEASE, "agent");
    __syncthreads();
    if (tid == 0)
        __hip_atomic_store(&flags[blk * 16], gen, __ATOMIC_RELAXED,
                           __HIP_MEMORY_SCOPE_AGENT);
    if (tid < 256) {
        while ((int)(__hip_atomic_load(&flags[tid * 16], __ATOMIC_RELAXED,
                                       __HIP_MEMORY_SCOPE_AGENT) - gen) < 0) {}
    }
    // acquire: invalidate per-XCD L2 so fresh h tiles are re-fetched
    __builtin_amdgcn_fence(__ATOMIC_ACQUIRE, "agent");
    __syncthreads();
}

// Cooperative kernel: 256 blocks x 512 threads, 1 block/CU.
// block -> (layer = blk & 7, slice = blk >> 3). Each block owns 16 LSTM units
// = 64 gate rows (i,f,g,o x16), weights resident in LDS for all 256 steps.
// Wavefront pipeline: layer l computes timestep t at superstep s = l + t.
__global__ void lstm_main(const float* __restrict__ x,
                          const float* __restrict__ w_ih,
                          const float* __restrict__ w_hh,
                          const float* __restrict__ b_ih,
                          const float* __restrict__ b_hh,
                          bf16_t* __restrict__ x_bf,    // [T][B][H]
                          bf16_t* __restrict__ h_buf,   // [L][2][B][H]
                          float*  __restrict__ finals,  // [B][L][H]
                          unsigned* __restrict__ flags)
{
    extern __shared__ char smem[];
    bf16_t* wlds  = (bf16_t*)(smem + W_OFF);
    float*  gates = (float*)(smem + GATES_OFF);
    float*  cst   = (float*)(smem + C_OFF);
    float*  bias  = (float*)(smem + BIAS_OFF);

    const int tid   = threadIdx.x;
    const int blk   = blockIdx.x;
    const int layer = blk & 7;
    const int slice = blk >> 3;
    const int u0    = slice * UNITS;
    unsigned gen = 0;

    // ---- prep: x -> bf16 transposed [t][b][e]; zero h ping-pong buffers ----
    {
        const int gtid = blk * blockDim.x + tid;
        const int nthr = gridDim.x * blockDim.x;   // 131072
        for (int i = gtid; i < BATCH * TSEQ * HDIM; i += nthr) {
            int e = i & (HDIM - 1);
            int b = (i >> 9) & 63;
            int t = i >> 15;
            x_bf[i] = (bf16_t)x[((size_t)b * TSEQ + t) * HDIM + e];
        }
        for (int i = gtid; i < LAYERS * 2 * BATCH * HDIM; i += nthr)
            h_buf[i] = (bf16_t)0.0f;
    }

    // ---- load this block's weight slice into LDS (bf16), rows = 64 gates ----
    // row r: gate = (r>>4)*512 + u0 + (r&15)   (i/f/g/o quadruple layout)
    for (int r = 0; r < NROWS; ++r) {
        const int gate = ((r >> 4) * 512) + u0 + (r & 15);
        const float* srcA = w_ih + ((size_t)layer * GDIM + gate) * HDIM;
        const float* srcB = w_hh + ((size_t)layer * GDIM + gate) * HDIM;
        wlds[r * WROW + tid]       = (bf16_t)srcA[tid];   // k in [0,512)
        wlds[r * WROW + 512 + tid] = (bf16_t)srcB[tid];   // k in [512,1024)
    }
    if (tid < NROWS) {
        const int gate = ((tid >> 4) * 512) + u0 + (tid & 15);
        bias[tid] = b_ih[layer * GDIM + gate] + b_hh[layer * GDIM + gate];
    }
    for (int i = tid; i < BATCH * UNITS; i += blockDim.x) cst[i] = 0.0f;

    grid_barrier(flags, ++gen, blk, tid);

    // ---- wave/tile assignment: 8 waves, each owns m-tile (batch16) x 2 n-tiles
    const int lane = tid & 63;
    const int wave = tid >> 6;
    const int quad = lane >> 4;
    const int l15  = lane & 15;
    const int m0   = (wave & 3) * 16;        // batch tile base
    const int nb0  = (wave >> 2) * 32;       // first of two 16-gate n-tiles

    const int arow = m0 + l15;
    const bf16_t* b_base0 = wlds + (size_t)(nb0 + l15) * WROW + quad * 8;
    const bf16_t* b_base1 = b_base0 + (size_t)16 * WROW;

    for (int s = 0; s < TSEQ + LAYERS - 1; ++s) {
        const int t = s - layer;
        if (t >= 0 && t < TSEQ) {
            const int p = s & 1;
            const bf16_t* src_lo = (layer == 0)
                ? (x_bf + (size_t)t * BATCH * HDIM)
                : (h_buf + (((size_t)(layer - 1) * 2 + (p ^ 1)) * BATCH * HDIM));
            const bf16_t* src_hi =
                h_buf + (((size_t)layer * 2 + (p ^ 1)) * BATCH * HDIM);

            const bf16_t* a_lo = src_lo + (size_t)arow * HDIM + quad * 8;
            const bf16_t* a_hi = src_hi + (size_t)arow * HDIM + quad * 8;

            floatx4 acc0 = {0.f, 0.f, 0.f, 0.f};
            floatx4 acc1 = {0.f, 0.f, 0.f, 0.f};

            #pragma unroll 4
            for (int kk = 0; kk < 16; ++kk) {
                bf16x8 a  = *(const bf16x8*)(a_lo + kk * 32);
                bf16x8 b0 = *(const bf16x8*)(b_base0 + kk * 32);
                bf16x8 b1 = *(const bf16x8*)(b_base1 + kk * 32);
                acc0 = mfma16(a, b0, acc0);
                acc1 = mfma16(a, b1, acc1);
            }
            #pragma unroll 4
            for (int kk = 0; kk < 16; ++kk) {
                bf16x8 a  = *(const bf16x8*)(a_hi + kk * 32);
                bf16x8 b0 = *(const bf16x8*)(b_base0 + 512 + kk * 32);
                bf16x8 b1 = *(const bf16x8*)(b_base1 + 512 + kk * 32);
                acc0 = mfma16(a, b0, acc0);
                acc1 = mfma16(a, b1, acc1);
            }

            // C/D layout: row = quad*4 + reg (batch), col = lane&15 (gate)
            #pragma unroll
            for (int r = 0; r < 4; ++r) {
                const int brow = m0 + quad * 4 + r;
                gates[brow * NROWS + nb0 + l15]      = acc0[r];
                gates[brow * NROWS + nb0 + 16 + l15] = acc1[r];
            }
            __syncthreads();

            // cell update: 64 batch x 16 units = 1024 items over 512 threads
            #pragma unroll
            for (int it = 0; it < 2; ++it) {
                const int id = tid + it * 512;
                const int b  = id >> 4;
                const int j  = id & 15;
                const float iv = gates[b * NROWS + j]      + bias[j];
                const float fv = gates[b * NROWS + 16 + j] + bias[16 + j];
                const float gv = gates[b * NROWS + 32 + j] + bias[32 + j];
                const float ov = gates[b * NROWS + 48 + j] + bias[48 + j];
                const float cold = cst[b * UNITS + j];
                const float cnew = sigm(fv) * cold + sigm(iv) * tanhf(gv);
                const float h    = sigm(ov) * tanhf(cnew);
                cst[b * UNITS + j] = cnew;
                h_buf[(((size_t)layer * 2 + p) * BATCH + b) * HDIM + u0 + j] =
                    (bf16_t)h;
                if (t == TSEQ - 1)
                    finals[((size_t)b * LAYERS + layer) * HDIM + u0 + j] = h;
            }
        }
        if (s < TSEQ + LAYERS - 2)
            grid_barrier(flags, ++gen, blk, tid);
    }
}

// FF head: per (b,l): 512 -> silu(128) -> 64, then interleave split + softplus.
__global__ void ff_epilogue(const float* __restrict__ finals,  // [B][L][H]
                            const float* __restrict__ ff1_w,   // [128][512]
                            const float* __restrict__ ff1_b,
                            const float* __restrict__ ff2_w,   // [64][128]
                            const float* __restrict__ ff2_b,
                            float* __restrict__ out)           // mean|scale
{
    __shared__ float fin[HDIM];
    __shared__ float hid[128];
    const int blk = blockIdx.x;        // b*8 + l
    const int b = blk >> 3, l = blk & 7;
    const int tid = threadIdx.x;       // 128

    const float* frow = finals + ((size_t)b * LAYERS + l) * HDIM;
    for (int k = tid; k < HDIM; k += 128) fin[k] = frow[k];
    __syncthreads();

    float acc = ff1_b[tid];
    const float* w1 = ff1_w + (size_t)tid * HDIM;
    #pragma unroll 4
    for (int k = 0; k < HDIM; ++k) acc = fmaf(fin[k], w1[k], acc);
    hid[tid] = acc * (1.0f / (1.0f + __expf(-acc)));   // silu
    __syncthreads();

    if (tid < 64) {
        float o = ff2_b[tid];
        const float* w2 = ff2_w + (size_t)tid * 128;
        #pragma unroll 4
        for (int k = 0; k < 128; ++k) o = fmaf(hid[k], w2[k], o);
        const int j = l * 64 + tid;        // column in (B, 512) flat h
        const int col = j >> 1;
        if ((j & 1) == 0) {
            out[b * 256 + col] = o;                        // mean
        } else {
            const float sp = fmaxf(o, 0.0f) + log1pf(__expf(-fabsf(o)));
            out[64 * 256 + b * 256 + col] = sp + 1e-8f;    // scale
        }
    }
}

extern "C" void kernel_launch(void* const* d_in, const int* in_sizes, int n_in,
                              void* d_out, int out_size, void* d_ws, size_t ws_size,
                              hipStream_t stream) {
    const float* x     = (const float*)d_in[0];
    const float* w_ih  = (const float*)d_in[1];
    const float* w_hh  = (const float*)d_in[2];
    const float* b_ih  = (const float*)d_in[3];
    const float* b_hh  = (const float*)d_in[4];
    const float* ff1_w = (const float*)d_in[5];
    const float* ff1_b = (const float*)d_in[6];
    const float* ff2_w = (const float*)d_in[7];
    const float* ff2_b = (const float*)d_in[8];
    float* out = (float*)d_out;

    char* ws = (char*)d_ws;
    bf16_t* x_bf   = (bf16_t*)ws;                                      // 16 MB
    bf16_t* h_buf  = (bf16_t*)(ws + (size_t)TSEQ * BATCH * HDIM * 2);  // 1 MB
    float*  finals = (float*)(ws + (size_t)TSEQ * BATCH * HDIM * 2
                                 + (size_t)LAYERS * 2 * BATCH * HDIM * 2); // 1 MB
    unsigned* flags = (unsigned*)(ws + (size_t)TSEQ * BATCH * HDIM * 2
                                     + (size_t)LAYERS * 2 * BATCH * HDIM * 2
                                     + (size_t)BATCH * LAYERS * HDIM * 4);  // 16 KB

    (void)in_sizes; (void)n_in; (void)out_size; (void)ws_size;

    hipFuncSetAttribute((const void*)lstm_main,
                        hipFuncAttributeMaxDynamicSharedMemorySize, LDS_TOTAL);

    void* args[] = {(void*)&x, (void*)&w_ih, (void*)&w_hh, (void*)&b_ih,
                    (void*)&b_hh, (void*)&x_bf, (void*)&h_buf, (void*)&finals,
                    (void*)&flags};
    hipLaunchCooperativeKernel((const void*)lstm_main, dim3(256), dim3(512),
                               args, LDS_TOTAL, stream);

    ff_epilogue<<<dim3(512), dim3(128), 0, stream>>>(finals, ff1_w, ff1_b,
                                                     ff2_w, ff2_b, out);
}

// Round 3
// 6309.911 us; speedup vs baseline: 1.8196x; 1.8196x over previous
//
#include <hip/hip_runtime.h>
#include <hip/hip_bf16.h>

typedef __bf16 bf16_t;
typedef __bf16 bf16x8 __attribute__((ext_vector_type(8)));
typedef float floatx4 __attribute__((ext_vector_type(4)));

#define LAYERS 8
#define BATCH  64
#define TSEQ   256
#define HDIM   512
#define GDIM   2048   // 4*H
#define UNITS  16     // LSTM units per CU slice
#define NROWS  64     // gate rows per CU slice (16 each of i,f,g,o)
#define WROW   1048   // weight row stride (bf16): stride 524 dw == 12 mod 32
#define GROW   65     // gates row stride (fp32): 65 == 1 mod 32 -> <=2-way
#define NSLOT  4      // h ring depth per layer (skew bound via back-pressure)

// LDS layout (bytes)
#define W_OFF       0
#define W_BYTES     (NROWS * WROW * 2)          // 134144
#define GATES_OFF   (W_OFF + W_BYTES)
#define GATES_BYTES (BATCH * GROW * 4)          // 16640
#define C_OFF       (GATES_OFF + GATES_BYTES)
#define C_BYTES     (BATCH * UNITS * 4)         // 4096
#define BIAS_OFF    (C_OFF + C_BYTES)
#define BIAS_BYTES  (NROWS * 4)                 // 256
#define LDS_TOTAL   (BIAS_OFF + BIAS_BYTES)     // 155136 < 160 KiB

__device__ __forceinline__ floatx4 mfma16(bf16x8 a, bf16x8 b, floatx4 c) {
    return __builtin_amdgcn_mfma_f32_16x16x32_bf16(a, b, c, 0, 0, 0);
}
__device__ __forceinline__ float sigm(float x) {
    return 1.0f / (1.0f + __expf(-x));
}
__device__ __forceinline__ unsigned pload(const unsigned* p) {
    return __hip_atomic_load(p, __ATOMIC_RELAXED, __HIP_MEMORY_SCOPE_AGENT);
}

// prep: x -> bf16 [t][b][e]; zero h ring; zero progress flags.
// Separate kernel => stream ordering guarantees init visible to lstm_main.
__global__ void prep(const float* __restrict__ x, bf16_t* __restrict__ x_bf,
                     bf16_t* __restrict__ h_buf, unsigned* __restrict__ prog) {
    const int gtid = blockIdx.x * blockDim.x + threadIdx.x;
    const int nthr = gridDim.x * blockDim.x;
    for (int i = gtid; i < BATCH * TSEQ * HDIM; i += nthr) {
        int e = i & (HDIM - 1);
        int b = (i >> 9) & 63;
        int t = i >> 15;
        x_bf[i] = (bf16_t)x[((size_t)b * TSEQ + t) * HDIM + e];
    }
    for (int i = gtid; i < LAYERS * NSLOT * BATCH * HDIM; i += nthr)
        h_buf[i] = (bf16_t)0.0f;
    for (int i = gtid; i < 256 * 16; i += nthr) prog[i] = 0u;
}

// Self-timed dataflow LSTM: 256 blocks x 512 threads, 1 block/CU (cooperative
// launch only for the co-residency guarantee -- there is NO grid barrier).
// block -> (layer = blk&7, slice = blk>>3); each block owns 16 units (64 gate
// rows), weights LDS-resident. Block runs its own t = 0..255 loop, gated by
// per-block monotonic progress flags:
//   c1: prog[layer-1][*] >= t+1   (producer h_{l-1}(t) stored)
//   c2: prog[layer  ][*] >= t     (own-layer h_l(t-1) stored)
//   c3: prog[layer+1][*] >= t-3   (back-pressure: ring slot t&3 free)
// h stores are write-through agent-scope relaxed atomics (u32 = 2 x bf16), so
// release needs only the vmcnt(0) drain already inside __syncthreads -- no
// buffer_wbl2 (the ~35 us/step killer in R1/R2). Acquire = cheap inv fence.
__global__ void lstm_main(const float* __restrict__ w_ih,
                          const float* __restrict__ w_hh,
                          const float* __restrict__ b_ih,
                          const float* __restrict__ b_hh,
                          const bf16_t* __restrict__ x_bf,  // [T][B][H]
                          bf16_t* __restrict__ h_buf,       // [L][4][B][H]
                          float*  __restrict__ finals,      // [B][L][H]
                          unsigned* __restrict__ prog)      // [256] x 16-dw
{
    extern __shared__ char smem[];
    bf16_t* wlds  = (bf16_t*)(smem + W_OFF);
    float*  gates = (float*)(smem + GATES_OFF);
    float*  cst   = (float*)(smem + C_OFF);
    float*  bias  = (float*)(smem + BIAS_OFF);

    const int tid   = threadIdx.x;
    const int blk   = blockIdx.x;
    const int layer = blk & 7;
    const int slice = blk >> 3;
    const int u0    = slice * UNITS;

    // ---- weights -> LDS (bf16); row r: gate = (r>>4)*512 + u0 + (r&15) ----
    for (int r = 0; r < NROWS; ++r) {
        const int gate = ((r >> 4) * 512) + u0 + (r & 15);
        const float* srcA = w_ih + ((size_t)layer * GDIM + gate) * HDIM;
        const float* srcB = w_hh + ((size_t)layer * GDIM + gate) * HDIM;
        wlds[r * WROW + tid]       = (bf16_t)srcA[tid];
        wlds[r * WROW + 512 + tid] = (bf16_t)srcB[tid];
    }
    if (tid < NROWS) {
        const int gate = ((tid >> 4) * 512) + u0 + (tid & 15);
        bias[tid] = b_ih[layer * GDIM + gate] + b_hh[layer * GDIM + gate];
    }
    for (int i = tid; i < BATCH * UNITS; i += blockDim.x) cst[i] = 0.0f;
    __syncthreads();

    // ---- wave/tile assignment: 8 waves, m-tile (16 batch) x 2 n-tiles ----
    const int lane = tid & 63;
    const int wave = tid >> 6;
    const int quad = lane >> 4;
    const int l15  = lane & 15;
    const int m0   = (wave & 3) * 16;
    const int nb0  = (wave >> 2) * 32;
    const int arow = m0 + l15;
    const bf16_t* b_base0 = wlds + (size_t)(nb0 + l15) * WROW + quad * 8;
    const bf16_t* b_base1 = b_base0 + (size_t)16 * WROW;

    // cell-update assignment: thread -> (batch b, unit pair 2*jp, 2*jp+1)
    const int cb = tid >> 3;
    const int jp = tid & 7;

    const int i32 = tid & 31;

    for (int t = 0; t < TSEQ; ++t) {
        // ---- self-timed waits (3 conditions on 3 different waves) ----
        if (tid < 32) {                      // wave 0: producer layer
            if (layer > 0) {
                const unsigned* f = prog + ((i32 << 3) + layer - 1) * 16;
                while (pload(f) < (unsigned)(t + 1)) {}
            }
        } else if (tid >= 64 && tid < 96) {  // wave 1: own layer
            if (t > 0) {
                const unsigned* f = prog + ((i32 << 3) + layer) * 16;
                while (pload(f) < (unsigned)t) {}
            }
        } else if (tid >= 128 && tid < 160) { // wave 2: back-pressure
            if (layer < 7 && t >= NSLOT) {
                const unsigned* f = prog + ((i32 << 3) + layer + 1) * 16;
                while (pload(f) < (unsigned)(t - 3)) {}
            }
        }
        __syncthreads();
        __builtin_amdgcn_fence(__ATOMIC_ACQUIRE, "agent");  // inv L1/L2

        const int slot  = t & (NSLOT - 1);
        const int pslot = (t + NSLOT - 1) & (NSLOT - 1);    // t-1 (t=0 -> 3, zeroed)
        const bf16_t* src_lo = (layer == 0)
            ? (x_bf + (size_t)t * BATCH * HDIM)
            : (h_buf + (((size_t)(layer - 1) * NSLOT + slot) * BATCH * HDIM));
        const bf16_t* src_hi =
            h_buf + (((size_t)layer * NSLOT + pslot) * BATCH * HDIM);

        const bf16_t* a_lo = src_lo + (size_t)arow * HDIM + quad * 8;
        const bf16_t* a_hi = src_hi + (size_t)arow * HDIM + quad * 8;

        floatx4 acc0 = {0.f, 0.f, 0.f, 0.f};
        floatx4 acc1 = {0.f, 0.f, 0.f, 0.f};

        #pragma unroll 4
        for (int kk = 0; kk < 16; ++kk) {
            bf16x8 a  = *(const bf16x8*)(a_lo + kk * 32);
            bf16x8 b0 = *(const bf16x8*)(b_base0 + kk * 32);
            bf16x8 b1 = *(const bf16x8*)(b_base1 + kk * 32);
            acc0 = mfma16(a, b0, acc0);
            acc1 = mfma16(a, b1, acc1);
        }
        #pragma unroll 4
        for (int kk = 0; kk < 16; ++kk) {
            bf16x8 a  = *(const bf16x8*)(a_hi + kk * 32);
            bf16x8 b0 = *(const bf16x8*)(b_base0 + 512 + kk * 32);
            bf16x8 b1 = *(const bf16x8*)(b_base1 + 512 + kk * 32);
            acc0 = mfma16(a, b0, acc0);
            acc1 = mfma16(a, b1, acc1);
        }

        // C/D layout: row = quad*4 + reg (batch), col = lane&15 (gate)
        #pragma unroll
        for (int r = 0; r < 4; ++r) {
            const int brow = m0 + quad * 4 + r;
            gates[brow * GROW + nb0 + l15]      = acc0[r];
            gates[brow * GROW + nb0 + 16 + l15] = acc1[r];
        }
        __syncthreads();

        // ---- cell update: (b, 2 units) per thread; packed u32 h store ----
        {
            const int j0 = jp * 2, j1 = j0 + 1;
            const float* g = gates + cb * GROW;
            const float iv0 = g[j0]      + bias[j0];
            const float fv0 = g[16 + j0] + bias[16 + j0];
            const float gv0 = g[32 + j0] + bias[32 + j0];
            const float ov0 = g[48 + j0] + bias[48 + j0];
            const float iv1 = g[j1]      + bias[j1];
            const float fv1 = g[16 + j1] + bias[16 + j1];
            const float gv1 = g[32 + j1] + bias[32 + j1];
            const float ov1 = g[48 + j1] + bias[48 + j1];
            const float c0 = sigm(fv0) * cst[cb * UNITS + j0]
                           + sigm(iv0) * tanhf(gv0);
            const float c1 = sigm(fv1) * cst[cb * UNITS + j1]
                           + sigm(iv1) * tanhf(gv1);
            cst[cb * UNITS + j0] = c0;
            cst[cb * UNITS + j1] = c1;
            const float h0 = sigm(ov0) * tanhf(c0);
            const float h1 = sigm(ov1) * tanhf(c1);
            const bf16_t hb0 = (bf16_t)h0, hb1 = (bf16_t)h1;
            const uint32_t u =
                ((uint32_t)__builtin_bit_cast(unsigned short, hb1) << 16) |
                (uint32_t)__builtin_bit_cast(unsigned short, hb0);
            uint32_t* dst = (uint32_t*)(h_buf +
                (((size_t)layer * NSLOT + slot) * BATCH + cb) * HDIM
                + u0 + j0);
            __hip_atomic_store(dst, u, __ATOMIC_RELAXED,
                               __HIP_MEMORY_SCOPE_AGENT);   // write-through
            if (t == TSEQ - 1) {
                float2 f2 = make_float2(h0, h1);
                *(float2*)(finals + ((size_t)cb * LAYERS + layer) * HDIM
                           + u0 + j0) = f2;
            }
        }
        // __syncthreads embeds s_waitcnt vmcnt(0): all write-through h stores
        // acked at the coherence point before the flag publish below.
        __syncthreads();
        if (tid == 0)
            __hip_atomic_store(prog + blk * 16, (unsigned)(t + 1),
                               __ATOMIC_RELAXED, __HIP_MEMORY_SCOPE_AGENT);
    }
}

// FF head: per (b,l): 512 -> silu(128) -> 64, interleave split + softplus.
__global__ void ff_epilogue(const float* __restrict__ finals,  // [B][L][H]
                            const float* __restrict__ ff1_w,   // [128][512]
                            const float* __restrict__ ff1_b,
                            const float* __restrict__ ff2_w,   // [64][128]
                            const float* __restrict__ ff2_b,
                            float* __restrict__ out)           // mean|scale
{
    __shared__ float fin[HDIM];
    __shared__ float hid[128];
    const int blk = blockIdx.x;        // b*8 + l
    const int b = blk >> 3, l = blk & 7;
    const int tid = threadIdx.x;       // 128

    const float* frow = finals + ((size_t)b * LAYERS + l) * HDIM;
    for (int k = tid; k < HDIM; k += 128) fin[k] = frow[k];
    __syncthreads();

    float acc = ff1_b[tid];
    const float* w1 = ff1_w + (size_t)tid * HDIM;
    #pragma unroll 4
    for (int k = 0; k < HDIM; ++k) acc = fmaf(fin[k], w1[k], acc);
    hid[tid] = acc * (1.0f / (1.0f + __expf(-acc)));   // silu
    __syncthreads();

    if (tid < 64) {
        float o = ff2_b[tid];
        const float* w2 = ff2_w + (size_t)tid * 128;
        #pragma unroll 4
        for (int k = 0; k < 128; ++k) o = fmaf(hid[k], w2[k], o);
        const int j = l * 64 + tid;        // column in (B, 512) flat h
        const int col = j >> 1;
        if ((j & 1) == 0) {
            out[b * 256 + col] = o;                        // mean
        } else {
            const float sp = fmaxf(o, 0.0f) + log1pf(__expf(-fabsf(o)));
            out[64 * 256 + b * 256 + col] = sp + 1e-8f;    // scale
        }
    }
}

extern "C" void kernel_launch(void* const* d_in, const int* in_sizes, int n_in,
                              void* d_out, int out_size, void* d_ws, size_t ws_size,
                              hipStream_t stream) {
    const float* x     = (const float*)d_in[0];
    const float* w_ih  = (const float*)d_in[1];
    const float* w_hh  = (const float*)d_in[2];
    const float* b_ih  = (const float*)d_in[3];
    const float* b_hh  = (const float*)d_in[4];
    const float* ff1_w = (const float*)d_in[5];
    const float* ff1_b = (const float*)d_in[6];
    const float* ff2_w = (const float*)d_in[7];
    const float* ff2_b = (const float*)d_in[8];
    float* out = (float*)d_out;

    char* ws = (char*)d_ws;
    bf16_t* x_bf   = (bf16_t*)ws;                                   // 16 MB
    size_t off = (size_t)TSEQ * BATCH * HDIM * 2;
    bf16_t* h_buf  = (bf16_t*)(ws + off);                           // 2 MB
    off += (size_t)LAYERS * NSLOT * BATCH * HDIM * 2;
    float*  finals = (float*)(ws + off);                            // 1 MB
    off += (size_t)BATCH * LAYERS * HDIM * 4;
    unsigned* prog = (unsigned*)(ws + off);                         // 16 KB

    (void)in_sizes; (void)n_in; (void)out_size; (void)ws_size;

    hipFuncSetAttribute((const void*)lstm_main,
                        hipFuncAttributeMaxDynamicSharedMemorySize, LDS_TOTAL);

    prep<<<dim3(1024), dim3(256), 0, stream>>>(x, x_bf, h_buf, prog);

    void* args[] = {(void*)&w_ih, (void*)&w_hh, (void*)&b_ih, (void*)&b_hh,
                    (void*)&x_bf, (void*)&h_buf, (void*)&finals, (void*)&prog};
    hipLaunchCooperativeKernel((const void*)lstm_main, dim3(256), dim3(512),
                               args, LDS_TOTAL, stream);

    ff_epilogue<<<dim3(512), dim3(128), 0, stream>>>(finals, ff1_w, ff1_b,
                                                     ff2_w, ff2_b, out);
}

// Round 4
// 3036.254 us; speedup vs baseline: 3.7814x; 2.0782x over previous
//
#include <hip/hip_runtime.h>
#include <hip/hip_bf16.h>

typedef __bf16 bf16_t;
typedef __bf16 bf16x8 __attribute__((ext_vector_type(8)));
typedef float floatx4 __attribute__((ext_vector_type(4)));

#define LAYERS 8
#define BATCH  64
#define TSEQ   256
#define HDIM   512
#define GDIM   2048   // 4*H
#define UNITS  16     // LSTM units per CU slice
#define NROWS  64     // gate rows per CU slice (16 each of i,f,g,o)
#define WROW   1048   // weight row stride (bf16)
#define GROW   65     // gates row stride (fp32)
#define MAXM   257    // full-sequence slots: 256 steps + 1 zero slot => NO reuse

// LDS layout (bytes)
#define W_OFF       0
#define W_BYTES     (NROWS * WROW * 2)          // 134144
#define GATES_OFF   (W_OFF + W_BYTES)
#define GATES_BYTES (BATCH * GROW * 4)          // 16640
#define C_OFF       (GATES_OFF + GATES_BYTES)
#define C_BYTES     (BATCH * UNITS * 4)         // 4096
#define BIAS_OFF    (C_OFF + C_BYTES)
#define BIAS_BYTES  (NROWS * 4)                 // 256
#define LDS_TOTAL   (BIAS_OFF + BIAS_BYTES)     // 155136 < 160 KiB

__device__ __forceinline__ floatx4 mfma16(bf16x8 a, bf16x8 b, floatx4 c) {
    return __builtin_amdgcn_mfma_f32_16x16x32_bf16(a, b, c, 0, 0, 0);
}
__device__ __forceinline__ float sigm(float x) {
    return 1.0f / (1.0f + __expf(-x));
}
__device__ __forceinline__ unsigned pload(const unsigned* p) {
    return __hip_atomic_load(p, __ATOMIC_RELAXED, __HIP_MEMORY_SCOPE_AGENT);
}

// prep: x -> bf16 [t][b][e]; zero each layer's slot-0 (the t=-1 "h"=0 page);
// zero progress flags. Separate dispatch => visible to lstm_main by stream order.
__global__ void prep(const float* __restrict__ x, bf16_t* __restrict__ x_bf,
                     bf16_t* __restrict__ h_buf, unsigned* __restrict__ prog,
                     int M) {
    const int gtid = blockIdx.x * blockDim.x + threadIdx.x;
    const int nthr = gridDim.x * blockDim.x;
    for (int i = gtid; i < BATCH * TSEQ * HDIM; i += nthr) {
        int e = i & (HDIM - 1);
        int b = (i >> 9) & 63;
        int t = i >> 15;
        x_bf[i] = (bf16_t)x[((size_t)b * TSEQ + t) * HDIM + e];
    }
    const size_t lstride = (size_t)M * BATCH * HDIM;
    for (int i = gtid; i < LAYERS * BATCH * HDIM; i += nthr) {
        int l   = i / (BATCH * HDIM);
        int off = i % (BATCH * HDIM);
        h_buf[(size_t)l * lstride + off] = (bf16_t)0.0f;
    }
    for (int i = gtid; i < 256 * 16; i += nthr) prog[i] = 0u;
}

// Self-timed dataflow LSTM: 256 blocks x 512 threads, 1 block/CU (cooperative
// launch for co-residency only -- no grid barrier, and with M=257 NO acquire
// fences on the hot path). block -> (layer=blk&7, slice=blk>>3).
//
// Coherence scheme (the R3 fix): h lives in [L][M][B][H] with M=257 -- write
// slot t+1, read own-layer slot t (slot 0 = zeros), producer slot t+1. With
// M=257 no address is reused within a dispatch, so a consumer XCD's L1/L2 can
// never hold a stale copy: first demand miss fetches from L3, where the
// producer's write-through agent-scope store already landed (ack'd by the
// vmcnt(0) inside __syncthreads before the flag publish). This removes the
// per-step buffer_inv (full L2 invalidate) that burned ~20us/step in R3 by
// wiping all 32 co-XCD blocks' L2 lines every iteration.
// If ws_size is too small for M=257, host shrinks M; then one agent-acquire
// fence every F=M-1 steps (amortized) covers ring-slot reuse.
__global__ void lstm_main(const float* __restrict__ w_ih,
                          const float* __restrict__ w_hh,
                          const float* __restrict__ b_ih,
                          const float* __restrict__ b_hh,
                          const bf16_t* __restrict__ x_bf,  // [T][B][H]
                          bf16_t* __restrict__ h_buf,       // [L][M][B][H]
                          float*  __restrict__ finals,      // [B][L][H]
                          unsigned* __restrict__ prog,      // [256] x 16-dw
                          int M, int F)
{
    extern __shared__ char smem[];
    bf16_t* wlds  = (bf16_t*)(smem + W_OFF);
    float*  gates = (float*)(smem + GATES_OFF);
    float*  cst   = (float*)(smem + C_OFF);
    float*  bias  = (float*)(smem + BIAS_OFF);

    const int tid   = threadIdx.x;
    const int blk   = blockIdx.x;
    const int layer = blk & 7;
    const int slice = blk >> 3;
    const int u0    = slice * UNITS;
    const size_t lstride = (size_t)M * BATCH * HDIM;

    // ---- weights -> LDS (bf16); row r: gate = (r>>4)*512 + u0 + (r&15) ----
    for (int r = 0; r < NROWS; ++r) {
        const int gate = ((r >> 4) * 512) + u0 + (r & 15);
        const float* srcA = w_ih + ((size_t)layer * GDIM + gate) * HDIM;
        const float* srcB = w_hh + ((size_t)layer * GDIM + gate) * HDIM;
        wlds[r * WROW + tid]       = (bf16_t)srcA[tid];
        wlds[r * WROW + 512 + tid] = (bf16_t)srcB[tid];
    }
    if (tid < NROWS) {
        const int gate = ((tid >> 4) * 512) + u0 + (tid & 15);
        bias[tid] = b_ih[layer * GDIM + gate] + b_hh[layer * GDIM + gate];
    }
    for (int i = tid; i < BATCH * UNITS; i += blockDim.x) cst[i] = 0.0f;
    __syncthreads();

    // ---- wave/tile assignment: 8 waves, m-tile (16 batch) x 2 n-tiles ----
    const int lane = tid & 63;
    const int wave = tid >> 6;
    const int quad = lane >> 4;
    const int l15  = lane & 15;
    const int m0   = (wave & 3) * 16;
    const int nb0  = (wave >> 2) * 32;
    const int arow = m0 + l15;
    const bf16_t* b_base0 = wlds + (size_t)(nb0 + l15) * WROW + quad * 8;
    const bf16_t* b_base1 = b_base0 + (size_t)16 * WROW;

    // cell-update assignment: thread -> (batch cb, units 2*jp, 2*jp+1)
    const int cb = tid >> 3;
    const int jp = tid & 7;
    const int i32 = tid & 31;

    for (int t = 0; t < TSEQ; ++t) {
        // ---- self-timed waits (3 conditions on 3 different waves) ----
        if (tid < 32) {                      // c1: producer layer done step t
            if (layer > 0) {
                const unsigned* f = prog + ((i32 << 3) + layer - 1) * 16;
                while (pload(f) < (unsigned)(t + 1)) {}
            }
        } else if (tid >= 64 && tid < 96) {  // c2: own-layer siblings done t-1
            if (t > 0) {
                const unsigned* f = prog + ((i32 << 3) + layer) * 16;
                while (pload(f) < (unsigned)t) {}
            }
        } else if (tid >= 128 && tid < 160) { // c3: ring back-pressure (M<257)
            if (layer < 7 && t >= M - 1) {
                const unsigned* f = prog + ((i32 << 3) + layer + 1) * 16;
                while (pload(f) < (unsigned)(t - M + 2)) {}
            }
        }
        // compiler-ordering fence only (workgroup scope: no cache op emitted)
        __builtin_amdgcn_fence(__ATOMIC_ACQUIRE, "workgroup");
        if ((t % F) == 0)   // ring mode only; M=257 -> fires once at t=0
            __builtin_amdgcn_fence(__ATOMIC_ACQUIRE, "agent");
        __syncthreads();

        const int slot_w = (t + 1) % M;      // write h(t) here
        const int slot_o = t % M;            // own-layer h(t-1); slot 0 = zeros
        const bf16_t* src_lo = (layer == 0)
            ? (x_bf + (size_t)t * BATCH * HDIM)
            : (h_buf + (size_t)(layer - 1) * lstride
                     + (size_t)slot_w * BATCH * HDIM);
        const bf16_t* src_hi =
            h_buf + (size_t)layer * lstride + (size_t)slot_o * BATCH * HDIM;

        const bf16_t* a_lo = src_lo + (size_t)arow * HDIM + quad * 8;
        const bf16_t* a_hi = src_hi + (size_t)arow * HDIM + quad * 8;

        floatx4 acc0 = {0.f, 0.f, 0.f, 0.f};
        floatx4 acc1 = {0.f, 0.f, 0.f, 0.f};

        #pragma unroll 4
        for (int kk = 0; kk < 16; ++kk) {
            bf16x8 a  = *(const bf16x8*)(a_lo + kk * 32);
            bf16x8 b0 = *(const bf16x8*)(b_base0 + kk * 32);
            bf16x8 b1 = *(const bf16x8*)(b_base1 + kk * 32);
            acc0 = mfma16(a, b0, acc0);
            acc1 = mfma16(a, b1, acc1);
        }
        #pragma unroll 4
        for (int kk = 0; kk < 16; ++kk) {
            bf16x8 a  = *(const bf16x8*)(a_hi + kk * 32);
            bf16x8 b0 = *(const bf16x8*)(b_base0 + 512 + kk * 32);
            bf16x8 b1 = *(const bf16x8*)(b_base1 + 512 + kk * 32);
            acc0 = mfma16(a, b0, acc0);
            acc1 = mfma16(a, b1, acc1);
        }

        // C/D layout: row = quad*4 + reg (batch), col = lane&15 (gate)
        #pragma unroll
        for (int r = 0; r < 4; ++r) {
            const int brow = m0 + quad * 4 + r;
            gates[brow * GROW + nb0 + l15]      = acc0[r];
            gates[brow * GROW + nb0 + 16 + l15] = acc1[r];
        }
        __syncthreads();

        // ---- cell update: (cb, 2 units) per thread; packed u32 h store ----
        {
            const int j0 = jp * 2, j1 = j0 + 1;
            const float* g = gates + cb * GROW;
            const float iv0 = g[j0]      + bias[j0];
            const float fv0 = g[16 + j0] + bias[16 + j0];
            const float gv0 = g[32 + j0] + bias[32 + j0];
            const float ov0 = g[48 + j0] + bias[48 + j0];
            const float iv1 = g[j1]      + bias[j1];
            const float fv1 = g[16 + j1] + bias[16 + j1];
            const float gv1 = g[32 + j1] + bias[32 + j1];
            const float ov1 = g[48 + j1] + bias[48 + j1];
            const float c0 = sigm(fv0) * cst[cb * UNITS + j0]
                           + sigm(iv0) * tanhf(gv0);
            const float c1 = sigm(fv1) * cst[cb * UNITS + j1]
                           + sigm(iv1) * tanhf(gv1);
            cst[cb * UNITS + j0] = c0;
            cst[cb * UNITS + j1] = c1;
            const float h0 = sigm(ov0) * tanhf(c0);
            const float h1 = sigm(ov1) * tanhf(c1);
            const bf16_t hb0 = (bf16_t)h0, hb1 = (bf16_t)h1;
            const uint32_t u =
                ((uint32_t)__builtin_bit_cast(unsigned short, hb1) << 16) |
                (uint32_t)__builtin_bit_cast(unsigned short, hb0);
            uint32_t* dst = (uint32_t*)(h_buf + (size_t)layer * lstride
                + ((size_t)slot_w * BATCH + cb) * HDIM + u0 + j0);
            __hip_atomic_store(dst, u, __ATOMIC_RELAXED,
                               __HIP_MEMORY_SCOPE_AGENT);   // write-through
            if (t == TSEQ - 1) {
                float2 f2 = make_float2(h0, h1);
                *(float2*)(finals + ((size_t)cb * LAYERS + layer) * HDIM
                           + u0 + j0) = f2;
            }
        }
        // __syncthreads embeds s_waitcnt vmcnt(0): write-through h stores are
        // acked at the coherence point before the flag publish below.
        __syncthreads();
        if (tid == 0)
            __hip_atomic_store(prog + blk * 16, (unsigned)(t + 1),
                               __ATOMIC_RELAXED, __HIP_MEMORY_SCOPE_AGENT);
    }
}

// FF head: per (b,l): 512 -> silu(128) -> 64, interleave split + softplus.
__global__ void ff_epilogue(const float* __restrict__ finals,  // [B][L][H]
                            const float* __restrict__ ff1_w,   // [128][512]
                            const float* __restrict__ ff1_b,
                            const float* __restrict__ ff2_w,   // [64][128]
                            const float* __restrict__ ff2_b,
                            float* __restrict__ out)           // mean|scale
{
    __shared__ float fin[HDIM];
    __shared__ float hid[128];
    const int blk = blockIdx.x;        // b*8 + l
    const int b = blk >> 3, l = blk & 7;
    const int tid = threadIdx.x;       // 128

    const float* frow = finals + ((size_t)b * LAYERS + l) * HDIM;
    for (int k = tid; k < HDIM; k += 128) fin[k] = frow[k];
    __syncthreads();

    float acc = ff1_b[tid];
    const float* w1 = ff1_w + (size_t)tid * HDIM;
    #pragma unroll 4
    for (int k = 0; k < HDIM; ++k) acc = fmaf(fin[k], w1[k], acc);
    hid[tid] = acc * (1.0f / (1.0f + __expf(-acc)));   // silu
    __syncthreads();

    if (tid < 64) {
        float o = ff2_b[tid];
        const float* w2 = ff2_w + (size_t)tid * 128;
        #pragma unroll 4
        for (int k = 0; k < 128; ++k) o = fmaf(hid[k], w2[k], o);
        const int j = l * 64 + tid;        // column in (B, 512) flat h
        const int col = j >> 1;
        if ((j & 1) == 0) {
            out[b * 256 + col] = o;                        // mean
        } else {
            const float sp = fmaxf(o, 0.0f) + log1pf(__expf(-fabsf(o)));
            out[64 * 256 + b * 256 + col] = sp + 1e-8f;    // scale
        }
    }
}

extern "C" void kernel_launch(void* const* d_in, const int* in_sizes, int n_in,
                              void* d_out, int out_size, void* d_ws, size_t ws_size,
                              hipStream_t stream) {
    const float* x     = (const float*)d_in[0];
    const float* w_ih  = (const float*)d_in[1];
    const float* w_hh  = (const float*)d_in[2];
    const float* b_ih  = (const float*)d_in[3];
    const float* b_hh  = (const float*)d_in[4];
    const float* ff1_w = (const float*)d_in[5];
    const float* ff1_b = (const float*)d_in[6];
    const float* ff2_w = (const float*)d_in[7];
    const float* ff2_b = (const float*)d_in[8];
    float* out = (float*)d_out;

    // ws budget: x_bf 16MB + finals 1MB + prog 16KB + h_buf L*M*64KB
    const size_t fixed = (size_t)TSEQ * BATCH * HDIM * 2      // x_bf
                       + (size_t)BATCH * LAYERS * HDIM * 4    // finals
                       + 256 * 16 * 4 + 4096;                 // prog + slack
    const size_t per_slot = (size_t)LAYERS * BATCH * HDIM * 2; // 512KB / slot
    int M = MAXM;
    if (ws_size > fixed) {
        size_t fit = (ws_size - fixed) / per_slot;
        if (fit < (size_t)M) M = (int)fit;   // ring fallback (adds inv fences)
    }
    if (M < 5) M = 5;
    const int F = M - 1;

    char* ws = (char*)d_ws;
    bf16_t* x_bf = (bf16_t*)ws;
    size_t off = (size_t)TSEQ * BATCH * HDIM * 2;
    float* finals = (float*)(ws + off);
    off += (size_t)BATCH * LAYERS * HDIM * 4;
    unsigned* prog = (unsigned*)(ws + off);
    off += 256 * 16 * 4;
    off = (off + 255) & ~(size_t)255;
    bf16_t* h_buf = (bf16_t*)(ws + off);    // [L][M][B][H], ~128.5MB at M=257

    (void)in_sizes; (void)n_in; (void)out_size;

    hipFuncSetAttribute((const void*)lstm_main,
                        hipFuncAttributeMaxDynamicSharedMemorySize, LDS_TOTAL);

    prep<<<dim3(1024), dim3(256), 0, stream>>>(x, x_bf, h_buf, prog, M);

    void* args[] = {(void*)&w_ih, (void*)&w_hh, (void*)&b_ih, (void*)&b_hh,
                    (void*)&x_bf, (void*)&h_buf, (void*)&finals, (void*)&prog,
                    (void*)&M, (void*)&F};
    hipLaunchCooperativeKernel((const void*)lstm_main, dim3(256), dim3(512),
                               args, LDS_TOTAL, stream);

    ff_epilogue<<<dim3(512), dim3(128), 0, stream>>>(finals, ff1_w, ff1_b,
                                                     ff2_w, ff2_b, out);
}

// Round 5
// 2678.489 us; speedup vs baseline: 4.2865x; 1.1336x over previous
//
#include <hip/hip_runtime.h>
#include <hip/hip_bf16.h>

typedef __bf16 bf16_t;
typedef __bf16 bf16x8 __attribute__((ext_vector_type(8)));
typedef float floatx4 __attribute__((ext_vector_type(4)));

#define LAYERS 8
#define BATCH  64
#define TSEQ   256
#define HDIM   512
#define GDIM   2048   // 4*H
#define UNITS  16     // LSTM units per CU slice
#define NROWS  64     // gate rows per CU slice (16 each of i,f,g,o)
#define WROW   1048   // weight row stride (bf16)
#define GROW   65     // gates row stride (fp32)
#define MAXM   257    // h_x slots: full sequence => virgin addresses
#define NSS    16     // h_s sibling ring depth (reuse distance >> L1 capacity)

// LDS layout (bytes)
#define W_OFF       0
#define W_BYTES     (NROWS * WROW * 2)          // 134144
#define GATES_OFF   (W_OFF + W_BYTES)
#define GATES_BYTES (BATCH * GROW * 4)          // 16640
#define C_OFF       (GATES_OFF + GATES_BYTES)
#define C_BYTES     (BATCH * UNITS * 4)         // 4096
#define BIAS_OFF    (C_OFF + C_BYTES)
#define BIAS_BYTES  (NROWS * 4)                 // 256
#define LDS_TOTAL   (BIAS_OFF + BIAS_BYTES)     // 155136 < 160 KiB

__device__ __forceinline__ floatx4 mfma16(bf16x8 a, bf16x8 b, floatx4 c) {
    return __builtin_amdgcn_mfma_f32_16x16x32_bf16(a, b, c, 0, 0, 0);
}
__device__ __forceinline__ float sigm(float x) {
    return 1.0f / (1.0f + __expf(-x));
}
// agent-scope (cross-XCD, via L3) flag ops
__device__ __forceinline__ unsigned pload_x(const unsigned* p) {
    return __hip_atomic_load(p, __ATOMIC_RELAXED, __HIP_MEMORY_SCOPE_AGENT);
}
__device__ __forceinline__ void pstore_x(unsigned* p, unsigned v) {
    __hip_atomic_store(p, v, __ATOMIC_RELAXED, __HIP_MEMORY_SCOPE_AGENT);
}
// same-XCD flag poll: L1-bypass, L2-hit (sc0). HIP has no "XCD scope"; agent
// scope would bypass L2 to L3 (slow). Same-XCD L2 is the coherence point for
// the 32 sibling blocks (blk%8 -> XCD), so sc0 is sufficient and ~3x closer.
__device__ __forceinline__ unsigned poll_s(const unsigned* p) {
    unsigned v;
    asm volatile("global_load_dword %0, %1, off sc0\n\t"
                 "s_waitcnt vmcnt(0)"
                 : "=v"(v) : "v"(p) : "memory");
    return v;
}

// prep: x -> bf16 [t][b][e]; zero h_s ring; zero both flag arrays.
__global__ void prep(const float* __restrict__ x, bf16_t* __restrict__ x_bf,
                     bf16_t* __restrict__ h_s, unsigned* __restrict__ prog_x,
                     unsigned* __restrict__ prog_s) {
    const int gtid = blockIdx.x * blockDim.x + threadIdx.x;
    const int nthr = gridDim.x * blockDim.x;
    for (int i = gtid; i < BATCH * TSEQ * HDIM; i += nthr) {
        int e = i & (HDIM - 1);
        int b = (i >> 9) & 63;
        int t = i >> 15;
        x_bf[i] = (bf16_t)x[((size_t)b * TSEQ + t) * HDIM + e];
    }
    for (int i = gtid; i < LAYERS * NSS * BATCH * HDIM / 2; i += nthr)
        ((unsigned*)h_s)[i] = 0u;
    for (int i = gtid; i < 256 * 16; i += nthr) { prog_x[i] = 0u; prog_s[i] = 0u; }
}

// Self-timed dataflow LSTM, R5: the steady-state critical cycle is the
// WITHIN-LAYER recurrence h_l(t-1)->h_l(t) among 32 sibling blocks that share
// one XCD (blk%8 -> XCD). That cycle now runs entirely through the XCD's L2:
//   - h_s: sibling h ring (16 slots), PLAIN write-back stores (fast L2 ack),
//     plain loads (ring reuse distance 16 steps x ~256KB/step >> 32KB L1, so
//     stale L1 lines are structurally impossible).
//   - prog_s: plain store + sc0 poll (L1-bypass, L2-hit).
// Cross-XCD edges (h_x write-through + prog_x agent flags) are OFF the cycle:
// the c1 wait has pipeline slack, h_x stores are issued last and drained by
// the NEXT iteration's first barrier, and prog_x is published one step late.
// The c2 wait sits AFTER the lo-GEMM so producer-side latency hides in slack.
__global__ void lstm_main(const float* __restrict__ w_ih,
                          const float* __restrict__ w_hh,
                          const float* __restrict__ b_ih,
                          const float* __restrict__ b_hh,
                          const bf16_t* __restrict__ x_bf,  // [T][B][H]
                          bf16_t* __restrict__ h_x,         // [L][M][B][H]
                          bf16_t* __restrict__ h_s,         // [L][NSS][B][H]
                          float*  __restrict__ finals,      // [B][L][H]
                          unsigned* __restrict__ prog_x,    // [256] x 16-dw
                          unsigned* __restrict__ prog_s,    // [256] x 16-dw
                          int M, int F)
{
    extern __shared__ char smem[];
    bf16_t* wlds  = (bf16_t*)(smem + W_OFF);
    float*  gates = (float*)(smem + GATES_OFF);
    float*  cst   = (float*)(smem + C_OFF);
    float*  bias  = (float*)(smem + BIAS_OFF);

    const int tid   = threadIdx.x;
    const int blk   = blockIdx.x;
    const int layer = blk & 7;
    const int slice = blk >> 3;
    const int u0    = slice * UNITS;
    const size_t lstride = (size_t)M * BATCH * HDIM;
    const bool ringmode = (M < MAXM);

    // ---- weights -> LDS (bf16); row r: gate = (r>>4)*512 + u0 + (r&15) ----
    for (int r = 0; r < NROWS; ++r) {
        const int gate = ((r >> 4) * 512) + u0 + (r & 15);
        const float* srcA = w_ih + ((size_t)layer * GDIM + gate) * HDIM;
        const float* srcB = w_hh + ((size_t)layer * GDIM + gate) * HDIM;
        wlds[r * WROW + tid]       = (bf16_t)srcA[tid];
        wlds[r * WROW + 512 + tid] = (bf16_t)srcB[tid];
    }
    if (tid < NROWS) {
        const int gate = ((tid >> 4) * 512) + u0 + (tid & 15);
        bias[tid] = b_ih[layer * GDIM + gate] + b_hh[layer * GDIM + gate];
    }
    for (int i = tid; i < BATCH * UNITS; i += blockDim.x) cst[i] = 0.0f;
    __syncthreads();

    // ---- wave/tile assignment: 8 waves, m-tile (16 batch) x 2 n-tiles ----
    const int lane = tid & 63;
    const int wave = tid >> 6;
    const int quad = lane >> 4;
    const int l15  = lane & 15;
    const int m0   = (wave & 3) * 16;
    const int nb0  = (wave >> 2) * 32;
    const int arow = m0 + l15;
    const bf16_t* b_base0 = wlds + (size_t)(nb0 + l15) * WROW + quad * 8;
    const bf16_t* b_base1 = b_base0 + (size_t)16 * WROW;

    // cell-update assignment: thread -> (batch cb, units 2*jp, 2*jp+1)
    const int cb = tid >> 3;
    const int jp = tid & 3 | ((tid & 7) & ~3);  // = tid & 7
    const int i32 = tid & 31;

    for (int t = 0; t < TSEQ; ++t) {
        // ---- A: cross-layer poll (c1) + h_x ring back-pressure (c3) ----
        if (layer > 0 && tid < 32) {
            const unsigned* f = prog_x + ((i32 << 3) + layer - 1) * 16;
            while ((int)(pload_x(f) - (unsigned)(t + 1)) < 0) {}
        } else if (ringmode && layer < 7 && tid >= 128 && tid < 160 &&
                   t >= M - 1) {
            const unsigned* f = prog_x + ((i32 << 3) + layer + 1) * 16;
            while ((int)(pload_x(f) - (unsigned)(t + 2 - M)) < 0) {}
        }
        __syncthreads();                 // B1: drains prev iter's h_x stores
        if (ringmode && (t % F) == 0)
            __builtin_amdgcn_fence(__ATOMIC_ACQUIRE, "agent");
        if (tid == 0 && t > 0)
            pstore_x(prog_x + blk * 16, (unsigned)t);  // h_x(<=t-1) visible

        // ---- B: lo-GEMM (x for layer 0, producer h_x otherwise) ----
        const int slot_lo = (t + 1) % M;
        const bf16_t* src_lo = (layer == 0)
            ? (x_bf + (size_t)t * BATCH * HDIM)
            : (h_x + (size_t)(layer - 1) * lstride
                   + (size_t)slot_lo * BATCH * HDIM);
        const bf16_t* a_lo = src_lo + (size_t)arow * HDIM + quad * 8;

        floatx4 acc0 = {0.f, 0.f, 0.f, 0.f};
        floatx4 acc1 = {0.f, 0.f, 0.f, 0.f};
        #pragma unroll 4
        for (int kk = 0; kk < 16; ++kk) {
            bf16x8 a  = *(const bf16x8*)(a_lo + kk * 32);
            bf16x8 b0 = *(const bf16x8*)(b_base0 + kk * 32);
            bf16x8 b1 = *(const bf16x8*)(b_base1 + kk * 32);
            acc0 = mfma16(a, b0, acc0);
            acc1 = mfma16(a, b1, acc1);
        }

        // ---- C: sibling poll (c2) -- after this wave's lo-GEMM ----
        if (t > 0 && tid >= 64 && tid < 96) {
            const unsigned* f = prog_s + ((i32 << 3) + layer) * 16;
            while ((int)(poll_s(f) - (unsigned)t) < 0) {}
        }
        __syncthreads();                 // C2

        // ---- D: hi-GEMM from sibling ring slot t-1 ----
        const bf16_t* a_hi = h_s
            + ((size_t)layer * NSS + ((t + NSS - 1) & (NSS - 1)))
              * BATCH * HDIM + (size_t)arow * HDIM + quad * 8;
        #pragma unroll 4
        for (int kk = 0; kk < 16; ++kk) {
            bf16x8 a  = *(const bf16x8*)(a_hi + kk * 32);
            bf16x8 b0 = *(const bf16x8*)(b_base0 + 512 + kk * 32);
            bf16x8 b1 = *(const bf16x8*)(b_base1 + 512 + kk * 32);
            acc0 = mfma16(a, b0, acc0);
            acc1 = mfma16(a, b1, acc1);
        }

        // C/D layout: row = quad*4 + reg (batch), col = lane&15 (gate)
        #pragma unroll
        for (int r = 0; r < 4; ++r) {
            const int brow = m0 + quad * 4 + r;
            gates[brow * GROW + nb0 + l15]      = acc0[r];
            gates[brow * GROW + nb0 + 16 + l15] = acc1[r];
        }
        __syncthreads();                 // E1

        // ---- E: cell update; h_s plain store (L2 write-back) ----
        float h0, h1;
        {
            const int j0 = jp * 2, j1 = j0 + 1;
            const float* g = gates + cb * GROW;
            const float iv0 = g[j0]      + bias[j0];
            const float fv0 = g[16 + j0] + bias[16 + j0];
            const float gv0 = g[32 + j0] + bias[32 + j0];
            const float ov0 = g[48 + j0] + bias[48 + j0];
            const float iv1 = g[j1]      + bias[j1];
            const float fv1 = g[16 + j1] + bias[16 + j1];
            const float gv1 = g[32 + j1] + bias[32 + j1];
            const float ov1 = g[48 + j1] + bias[48 + j1];
            const float c0 = sigm(fv0) * cst[cb * UNITS + j0]
                           + sigm(iv0) * tanhf(gv0);
            const float c1 = sigm(fv1) * cst[cb * UNITS + j1]
                           + sigm(iv1) * tanhf(gv1);
            cst[cb * UNITS + j0] = c0;
            cst[cb * UNITS + j1] = c1;
            h0 = sigm(ov0) * tanhf(c0);
            h1 = sigm(ov1) * tanhf(c1);
            const bf16_t hb0 = (bf16_t)h0, hb1 = (bf16_t)h1;
            const uint32_t u =
                ((uint32_t)__builtin_bit_cast(unsigned short, hb1) << 16) |
                (uint32_t)__builtin_bit_cast(unsigned short, hb0);
            uint32_t* dst_s = (uint32_t*)(h_s
                + ((size_t)layer * NSS + (t & (NSS - 1))) * BATCH * HDIM
                + (size_t)cb * HDIM + u0 + j0);
            __hip_atomic_store(dst_s, u, __ATOMIC_RELAXED,
                               __HIP_MEMORY_SCOPE_WORKGROUP);  // plain store
            if (t == TSEQ - 1) {
                *(float2*)(finals + ((size_t)cb * LAYERS + layer) * HDIM
                           + u0 + j0) = make_float2(h0, h1);
            }
        }
        __syncthreads();                 // E2: drains h_s (L2-fast; h_x not
                                         // yet issued this iter => no L3 wait)
        if (tid == 0)
            __hip_atomic_store(prog_s + blk * 16, (unsigned)(t + 1),
                               __ATOMIC_RELAXED, __HIP_MEMORY_SCOPE_WORKGROUP);

        // ---- F: cross-XCD h_x write-through (fire-and-forget; drained at
        //         next iteration's B1 barrier). Layer 7 has no consumer. ----
        if (layer < 7) {
            const int j0 = jp * 2;
            const bf16_t hb0 = (bf16_t)h0, hb1 = (bf16_t)h1;
            const uint32_t u =
                ((uint32_t)__builtin_bit_cast(unsigned short, hb1) << 16) |
                (uint32_t)__builtin_bit_cast(unsigned short, hb0);
            uint32_t* dst_x = (uint32_t*)(h_x + (size_t)layer * lstride
                + ((size_t)((t + 1) % M) * BATCH + (size_t)cb) * HDIM
                + u0 + j0);
            __hip_atomic_store(dst_x, u, __ATOMIC_RELAXED,
                               __HIP_MEMORY_SCOPE_AGENT);  // write-through
        }
    }
    // final cross publish (h_x(255) drained here)
    __syncthreads();
    if (tid == 0) pstore_x(prog_x + blk * 16, (unsigned)TSEQ);
}

// FF head: per (b,l): 512 -> silu(128) -> 64, interleave split + softplus.
__global__ void ff_epilogue(const float* __restrict__ finals,  // [B][L][H]
                            const float* __restrict__ ff1_w,   // [128][512]
                            const float* __restrict__ ff1_b,
                            const float* __restrict__ ff2_w,   // [64][128]
                            const float* __restrict__ ff2_b,
                            float* __restrict__ out)           // mean|scale
{
    __shared__ float fin[HDIM];
    __shared__ float hid[128];
    const int blk = blockIdx.x;        // b*8 + l
    const int b = blk >> 3, l = blk & 7;
    const int tid = threadIdx.x;       // 128

    const float* frow = finals + ((size_t)b * LAYERS + l) * HDIM;
    for (int k = tid; k < HDIM; k += 128) fin[k] = frow[k];
    __syncthreads();

    float acc = ff1_b[tid];
    const float* w1 = ff1_w + (size_t)tid * HDIM;
    #pragma unroll 4
    for (int k = 0; k < HDIM; ++k) acc = fmaf(fin[k], w1[k], acc);
    hid[tid] = acc * (1.0f / (1.0f + __expf(-acc)));   // silu
    __syncthreads();

    if (tid < 64) {
        float o = ff2_b[tid];
        const float* w2 = ff2_w + (size_t)tid * 128;
        #pragma unroll 4
        for (int k = 0; k < 128; ++k) o = fmaf(hid[k], w2[k], o);
        const int j = l * 64 + tid;        // column in (B, 512) flat h
        const int col = j >> 1;
        if ((j & 1) == 0) {
            out[b * 256 + col] = o;                        // mean
        } else {
            const float sp = fmaxf(o, 0.0f) + log1pf(__expf(-fabsf(o)));
            out[64 * 256 + b * 256 + col] = sp + 1e-8f;    // scale
        }
    }
}

extern "C" void kernel_launch(void* const* d_in, const int* in_sizes, int n_in,
                              void* d_out, int out_size, void* d_ws, size_t ws_size,
                              hipStream_t stream) {
    const float* x     = (const float*)d_in[0];
    const float* w_ih  = (const float*)d_in[1];
    const float* w_hh  = (const float*)d_in[2];
    const float* b_ih  = (const float*)d_in[3];
    const float* b_hh  = (const float*)d_in[4];
    const float* ff1_w = (const float*)d_in[5];
    const float* ff1_b = (const float*)d_in[6];
    const float* ff2_w = (const float*)d_in[7];
    const float* ff2_b = (const float*)d_in[8];
    float* out = (float*)d_out;

    char* ws = (char*)d_ws;
    bf16_t* x_bf = (bf16_t*)ws;                                    // 16 MB
    size_t off = (size_t)TSEQ * BATCH * HDIM * 2;
    float* finals = (float*)(ws + off);                            // 1 MB
    off += (size_t)BATCH * LAYERS * HDIM * 4;
    unsigned* prog_x = (unsigned*)(ws + off);  off += 256 * 16 * 4;
    unsigned* prog_s = (unsigned*)(ws + off);  off += 256 * 16 * 4;
    off = (off + 255) & ~(size_t)255;
    bf16_t* h_s = (bf16_t*)(ws + off);                             // 8 MB
    off += (size_t)LAYERS * NSS * BATCH * HDIM * 2;
    off = (off + 255) & ~(size_t)255;

    // size h_x from what's left (M=257 => fully virgin addressing)
    const size_t per_slot = (size_t)LAYERS * BATCH * HDIM * 2;     // 512 KB
    int M = MAXM;
    if (ws_size > off) {
        size_t fit = (ws_size - off) / per_slot;
        if (fit < (size_t)M) M = (int)fit;
    } else {
        M = 5;
    }
    if (M < 5) M = 5;
    const int F = M - 1;
    bf16_t* h_x = (bf16_t*)(ws + off);

    (void)in_sizes; (void)n_in; (void)out_size;

    hipFuncSetAttribute((const void*)lstm_main,
                        hipFuncAttributeMaxDynamicSharedMemorySize, LDS_TOTAL);

    prep<<<dim3(1024), dim3(256), 0, stream>>>(x, x_bf, h_s, prog_x, prog_s);

    void* args[] = {(void*)&w_ih, (void*)&w_hh, (void*)&b_ih, (void*)&b_hh,
                    (void*)&x_bf, (void*)&h_x, (void*)&h_s, (void*)&finals,
                    (void*)&prog_x, (void*)&prog_s, (void*)&M, (void*)&F};
    hipLaunchCooperativeKernel((const void*)lstm_main, dim3(256), dim3(512),
                               args, LDS_TOTAL, stream);

    ff_epilogue<<<dim3(512), dim3(128), 0, stream>>>(finals, ff1_w, ff1_b,
                                                     ff2_w, ff2_b, out);
}